// Round 10
// baseline (762.100 us; speedup 1.0000x reference)
//
#include <hip/hip_runtime.h>
#include <stdint.h>

#define N_NODES 100000
#define N_EDGES 1000000
#define D_IN 128
#define D_OUT 64
#define N_REL 4
#define OUT_STRIDE (N_REL * D_OUT)   // 256

#define M_SCAN (N_REL * N_NODES)     // 400000 (interleaved: idx = 4*node + rel)
#define SCHUNK 2048
#define NSB ((M_SCAN + SCHUNK - 1) / SCHUNK)   // 196 (<=256)
#define REL_CAP 2200000              // >= well above E[2M] masked entries

typedef short s16x8 __attribute__((ext_vector_type(8)));
typedef float f32x4 __attribute__((ext_vector_type(4)));

__device__ inline float b2f(unsigned short u) {
    union { unsigned int i; float f; } v;
    v.i = ((unsigned int)u) << 16;
    return v.f;
}
__device__ inline unsigned short f2b(float f) {
    union { float f; unsigned int i; } v;
    v.f = f;
    unsigned int r = v.i + 0x7FFF + ((v.i >> 16) & 1);   // rne
    return (unsigned short)(r >> 16);
}

// flag=1 if mask is 1-byte bools, 0 if int32
__global__ __launch_bounds__(256) void detect_mask_kernel(const uint8_t* __restrict__ mask,
                                                          int* __restrict__ flag) {
    int any = 0;
    for (int i = threadIdx.x; i < 65536; i += 256)
        if ((i & 3) && mask[i]) any = 1;
    if (any) atomicOr(flag, 1);
}

__device__ inline bool read_mask(const uint8_t* mask8, int bytemode, size_t idx) {
    return bytemode ? (mask8[idx] != 0) : (((const int*)mask8)[idx] != 0);
}

// all 4 masked in-degrees in ONE u64 atomic per edge (16-bit fields)
__global__ __launch_bounds__(256) void deg_kernel(const int* __restrict__ dst,
                                                  const uint8_t* __restrict__ mask,
                                                  const int* __restrict__ flag,
                                                  unsigned long long* __restrict__ degu) {
    int e = blockIdx.x * blockDim.x + threadIdx.x;
    if (e >= N_EDGES) return;
    int bm = *flag;
    int d = dst[e];
    unsigned long long inc = 0;
    if (read_mask(mask, bm, (size_t)0 * N_EDGES + e)) inc += 1ull;
    if (read_mask(mask, bm, (size_t)1 * N_EDGES + e)) inc += 1ull << 16;
    if (read_mask(mask, bm, (size_t)2 * N_EDGES + e)) inc += 1ull << 32;
    if (read_mask(mask, bm, (size_t)3 * N_EDGES + e)) inc += 1ull << 48;
    if (inc) atomicAdd(&degu[d], inc);
}

// norm[r*N+n] = 1/sqrt(max(deg_r[n],1))
__global__ __launch_bounds__(256) void norm_kernel(const unsigned long long* __restrict__ degu,
                                                   float* __restrict__ norm) {
    int n = blockIdx.x * blockDim.x + threadIdx.x;
    if (n >= N_NODES) return;
    unsigned long long u = degu[n];
#pragma unroll
    for (int r = 0; r < N_REL; ++r) {
        float dg = (float)((u >> (16 * r)) & 0xFFFF);
        norm[r * N_NODES + n] = 1.0f / sqrtf(fmaxf(dg, 1.0f));
    }
}

// INTERLEAVED scan index: i = 4*node + rel
__device__ inline int scan_val(const unsigned long long* degu, int i) {
    return (int)((degu[i >> 2] >> (16 * (i & 3))) & 0xFFFF);
}

// ---- 3-phase exclusive scan over interleaved masked degrees [4N] ----
__global__ __launch_bounds__(256) void scan_reduce_kernel(const unsigned long long* __restrict__ degu,
                                                          int* __restrict__ bsum) {
    __shared__ int sm[256];
    int b = blockIdx.x, t = threadIdx.x;
    int base = b * SCHUNK + t * 8;
    int s = 0;
#pragma unroll
    for (int i = 0; i < 8; ++i) {
        int idx = base + i;
        if (idx < M_SCAN) s += scan_val(degu, idx);
    }
    sm[t] = s;
    __syncthreads();
    for (int st = 128; st > 0; st >>= 1) {
        if (t < st) sm[t] += sm[t + st];
        __syncthreads();
    }
    if (t == 0) bsum[b] = sm[0];
}

__global__ __launch_bounds__(256) void scan_mid_kernel(const int* __restrict__ bsum,
                                                       int* __restrict__ boff,
                                                       int* __restrict__ rel_rp) {
    __shared__ int sm[256];
    int t = threadIdx.x;
    int v = (t < NSB) ? bsum[t] : 0;
    sm[t] = v;
    __syncthreads();
    for (int st = 1; st < 256; st <<= 1) {
        int u = (t >= st) ? sm[t - st] : 0;
        __syncthreads();
        sm[t] += u;
        __syncthreads();
    }
    if (t < NSB) boff[t] = sm[t] - v;              // exclusive block offset
    if (t == NSB - 1) rel_rp[M_SCAN] = sm[t];      // total masked entries
}

__global__ __launch_bounds__(256) void scan_final_kernel(const unsigned long long* __restrict__ degu,
                                                         const int* __restrict__ boff,
                                                         int* __restrict__ rel_rp,
                                                         int* __restrict__ cursor) {
    __shared__ int sm[256];
    int b = blockIdx.x, t = threadIdx.x;
    int base = b * SCHUNK + t * 8;
    int v[8];
    int s = 0;
#pragma unroll
    for (int i = 0; i < 8; ++i) {
        int idx = base + i;
        v[i] = (idx < M_SCAN) ? scan_val(degu, idx) : 0;
        s += v[i];
    }
    sm[t] = s;
    __syncthreads();
    for (int st = 1; st < 256; st <<= 1) {
        int u = (t >= st) ? sm[t - st] : 0;
        __syncthreads();
        sm[t] += u;
        __syncthreads();
    }
    int run = sm[t] - s + boff[b];
#pragma unroll
    for (int i = 0; i < 8; ++i) {
        int idx = base + i;
        if (idx < M_SCAN) { rel_rp[idx] = run; cursor[idx] = run; run += v[i]; }
    }
}

// compacted per-relation CSR (interleaved rows 4*d+r): only masked edges, src only.
// An edge's ~2 stores now land within the same node's contiguous entry region.
__global__ __launch_bounds__(256) void fill_kernel(const int* __restrict__ src,
                                                   const int* __restrict__ dst,
                                                   const uint8_t* __restrict__ mask,
                                                   const int* __restrict__ flag,
                                                   int* __restrict__ cursor,
                                                   int* __restrict__ rel_src) {
    int e = blockIdx.x * blockDim.x + threadIdx.x;
    if (e >= N_EDGES) return;
    int bm = *flag;
    int s = src[e], d = dst[e];
#pragma unroll
    for (int r = 0; r < N_REL; ++r) {
        if (read_mask(mask, bm, (size_t)r * N_EDGES + e)) {
            int pos = atomicAdd(&cursor[d * 4 + r], 1);
            rel_src[pos] = s;
        }
    }
}

// pack W[r][384][64] fp32 -> Wpk frags [r][ks][nb][lane][8] bf16
__global__ __launch_bounds__(256) void pack_w_kernel(const float* __restrict__ W,
                                                     unsigned short* __restrict__ Wpk) {
    int t = blockIdx.x * blockDim.x + threadIdx.x;   // 12288
    if (t >= N_REL * 12 * 4 * 64) return;
    int lane = t & 63;
    int nb   = (t >> 6) & 3;
    int ks   = (t >> 8) % 12;
    int r    = t / 3072;
    const float* Wr = W + (size_t)r * 384 * 64;
    int k0 = ks * 32 + (lane >> 4) * 8;
    int n  = nb * 16 + (lane & 15);
    unsigned short* o = Wpk + (size_t)t * 8;
#pragma unroll
    for (int i = 0; i < 8; ++i)
        o[i] = f2b(Wr[(size_t)(k0 + i) * 64 + n]);
}

// x fp32 -> bf16
__global__ __launch_bounds__(256) void xb_kernel(const float* __restrict__ x,
                                                 unsigned short* __restrict__ xb) {
    int i = blockIdx.x * blockDim.x + threadIdx.x;
    if (i >= N_NODES * (D_IN / 4)) return;
    float4 v = ((const float4*)x)[i];
    ushort4 u;
    u.x = f2b(v.x); u.y = f2b(v.y); u.z = f2b(v.z); u.w = f2b(v.w);
    ((ushort4*)xb)[i] = u;
}

// one hop over compacted interleaved CSR:
// hout[d] = bf16( norm[d] * sum_e norm[src]*hin[src] ), entries at rp[4*d+rel]
// wave per node; 4 edges in flight: 16-lane groups, 8 features/lane.
// ALL __shfl executed unconditionally (full exec mask).
template <int BF16IN>
__global__ __launch_bounds__(256) void gather_kernel(const void* __restrict__ hin_,
                                                     const int* __restrict__ rp,
                                                     const int* __restrict__ rel_src,
                                                     int rel,
                                                     const float* __restrict__ normr,
                                                     unsigned short* __restrict__ hout) {
    const int lane = threadIdx.x & 63;
    const int wid  = (blockIdx.x * blockDim.x + threadIdx.x) >> 6;   // node
    if (wid >= N_NODES) return;
    const int g  = lane >> 4;              // edge-slot group 0..3
    const int fb = (lane & 15) * 8;        // feature base (8 feats/lane)

    float a[8];
#pragma unroll
    for (int j = 0; j < 8; ++j) a[j] = 0.0f;

    int e0 = rp[wid * 4 + rel], e1 = rp[wid * 4 + rel + 1];
    for (int base = e0; base < e1; base += 64) {
        int m = min(64, e1 - base);
        int   s_l = (lane < m) ? rel_src[base + lane] : 0;
        float w_l = (lane < m) ? normr[s_l] : 0.0f;

        for (int t = 0; t * 4 < m; ++t) {
            int ei = t * 4 + g;                    // <= 63 always
            int   s = __shfl(s_l, ei);             // unconditional, full mask
            float w = __shfl(w_l, ei);
            if (ei < m) {                          // uniform per 16-lane group
                if (BF16IN) {
                    s16x8 v = *(const s16x8*)((const unsigned short*)hin_ +
                                              (size_t)s * D_IN + fb);
#pragma unroll
                    for (int j = 0; j < 8; ++j)
                        a[j] += w * b2f((unsigned short)v[j]);
                } else {
                    const float* xp = (const float*)hin_ + (size_t)s * D_IN + fb;
                    float4 v0 = *(const float4*)xp;
                    float4 v1 = *(const float4*)(xp + 4);
                    a[0] += w * v0.x; a[1] += w * v0.y;
                    a[2] += w * v0.z; a[3] += w * v0.w;
                    a[4] += w * v1.x; a[5] += w * v1.y;
                    a[6] += w * v1.z; a[7] += w * v1.w;
                }
            }
        }
    }

    // combine the 4 edge-slot groups (butterfly over lane bits 4,5)
#pragma unroll
    for (int j = 0; j < 8; ++j) {
        a[j] += __shfl_xor(a[j], 16);
        a[j] += __shfl_xor(a[j], 32);
    }
    float c = normr[wid];
    if (lane < 16) {
        s16x8 r;
#pragma unroll
        for (int j = 0; j < 8; ++j) r[j] = (short)f2b(a[j] * c);
        *(s16x8*)(hout + (size_t)wid * D_IN + lane * 8) = r;
    }
}

// MFMA GEMM: out[n][j] = relu(bias[j] + sum_k [x|h1|h2][n][k] W[k][j])
template <int XB16>
__global__ __launch_bounds__(256) void gemm_mfma_kernel(const void* __restrict__ x_,
                                                        const unsigned short* __restrict__ h1b,
                                                        const unsigned short* __restrict__ h2b,
                                                        const unsigned short* __restrict__ Wpk,
                                                        const float* __restrict__ bias,
                                                        float* __restrict__ out) {
    const int wave = threadIdx.x >> 6;
    const int lane = threadIdx.x & 63;
    const int rb   = blockIdx.x * 64 + wave * 16;
    const int row  = min(rb + (lane & 15), N_NODES - 1);
    const int kq   = (lane >> 4) * 8;

    f32x4 acc0 = {0.f, 0.f, 0.f, 0.f};
    f32x4 acc1 = {0.f, 0.f, 0.f, 0.f};
    f32x4 acc2 = {0.f, 0.f, 0.f, 0.f};
    f32x4 acc3 = {0.f, 0.f, 0.f, 0.f};

    const s16x8* Wf = (const s16x8*)Wpk;

#pragma unroll
    for (int ks = 0; ks < 12; ++ks) {
        s16x8 a;
        const int koff = (ks & 3) * 32 + kq;
        if (ks < 4) {
            if (XB16) {
                a = *(const s16x8*)((const unsigned short*)x_ + (size_t)row * D_IN + koff);
            } else {
                const float* p = (const float*)x_ + (size_t)row * D_IN + koff;
                float4 f0 = *(const float4*)p;
                float4 f1 = *(const float4*)(p + 4);
                a[0] = (short)f2b(f0.x); a[1] = (short)f2b(f0.y);
                a[2] = (short)f2b(f0.z); a[3] = (short)f2b(f0.w);
                a[4] = (short)f2b(f1.x); a[5] = (short)f2b(f1.y);
                a[6] = (short)f2b(f1.z); a[7] = (short)f2b(f1.w);
            }
        } else {
            const unsigned short* hp = (ks < 8) ? h1b : h2b;
            a = *(const s16x8*)(hp + (size_t)row * D_IN + koff);
        }
        const s16x8* bks = Wf + ks * 256 + lane;
        acc0 = __builtin_amdgcn_mfma_f32_16x16x32_bf16(a, bks[0],   acc0, 0, 0, 0);
        acc1 = __builtin_amdgcn_mfma_f32_16x16x32_bf16(a, bks[64],  acc1, 0, 0, 0);
        acc2 = __builtin_amdgcn_mfma_f32_16x16x32_bf16(a, bks[128], acc2, 0, 0, 0);
        acc3 = __builtin_amdgcn_mfma_f32_16x16x32_bf16(a, bks[192], acc3, 0, 0, 0);
    }

    const int orow0 = rb + (lane >> 4) * 4;
    const int jc    = lane & 15;
    f32x4 accs[4] = {acc0, acc1, acc2, acc3};
#pragma unroll
    for (int nb = 0; nb < 4; ++nb) {
        float bz = bias[nb * 16 + jc];
#pragma unroll
        for (int i = 0; i < 4; ++i) {
            int n = orow0 + i;
            if (n < N_NODES)
                out[(size_t)n * OUT_STRIDE + nb * 16 + jc] = fmaxf(accs[nb][i] + bz, 0.0f);
        }
    }
}

extern "C" void kernel_launch(void* const* d_in, const int* in_sizes, int n_in,
                              void* d_out, int out_size, void* d_ws, size_t ws_size,
                              hipStream_t stream) {
    const float*   x    = (const float*)d_in[0];
    const int*     src  = (const int*)d_in[1];
    const int*     dst  = (const int*)d_in[2];
    const uint8_t* mask = (const uint8_t*)d_in[3];
    const float*   W    = (const float*)d_in[4];     // [4][384][64]
    const float*   b    = (const float*)d_in[5];     // [4][64]
    float*         out  = (float*)d_out;             // [N][256]

    // ws: flag[64]i | degu[N]u64 | norm[4N]f | rel_rp[4N+16]i | bsum[256] |
    //     boff[256] | rel_src[REL_CAP]i | Wpk bf16 | h1b bf16 | h2b bf16 |
    //     xb bf16 (optional).  cursor aliases h1b (dead before gathers).
    int*                flag    = (int*)d_ws;
    unsigned long long* degu    = (unsigned long long*)((char*)d_ws + 256);
    float*              norm    = (float*)(degu + N_NODES);
    int*                rel_rp  = (int*)(norm + (size_t)N_REL * N_NODES);
    int*                bsum    = rel_rp + M_SCAN + 16;
    int*                boff    = bsum + 256;
    int*                rel_src = boff + 256;
    unsigned short*     Wpk     = (unsigned short*)(rel_src + REL_CAP);
    unsigned short*     h1b     = Wpk + 12288 * 8;
    unsigned short*     h2b     = h1b + (size_t)N_NODES * D_IN;
    unsigned short*     xb      = h2b + (size_t)N_NODES * D_IN;
    int*                cursor  = (int*)h1b;   // alias: used only pre-gather

    const size_t need_xb = (size_t)((char*)(xb + (size_t)N_NODES * D_IN) - (char*)d_ws);
    const int use_xb = (ws_size >= need_xb);

    // zero flag + degu
    hipMemsetAsync(d_ws, 0, 256 + (size_t)N_NODES * sizeof(unsigned long long), stream);

    detect_mask_kernel<<<1, 256, 0, stream>>>(mask, flag);
    deg_kernel<<<(N_EDGES + 255) / 256, 256, 0, stream>>>(dst, mask, flag, degu);
    norm_kernel<<<(N_NODES + 255) / 256, 256, 0, stream>>>(degu, norm);

    scan_reduce_kernel<<<NSB, 256, 0, stream>>>(degu, bsum);
    scan_mid_kernel<<<1, 256, 0, stream>>>(bsum, boff, rel_rp);
    scan_final_kernel<<<NSB, 256, 0, stream>>>(degu, boff, rel_rp, cursor);

    fill_kernel<<<(N_EDGES + 255) / 256, 256, 0, stream>>>(src, dst, mask, flag,
                                                           cursor, rel_src);
    pack_w_kernel<<<48, 256, 0, stream>>>(W, Wpk);
    if (use_xb)
        xb_kernel<<<(N_NODES * (D_IN / 4) + 255) / 256, 256, 0, stream>>>(x, xb);

    const int gather_grid = (N_NODES * 64 + 255) / 256;   // 1 wave per node
    const int gemm_grid   = (N_NODES + 63) / 64;

    for (int r = 0; r < N_REL; ++r) {
        const float* nr = norm + (size_t)r * N_NODES;

        if (use_xb)
            gather_kernel<1><<<gather_grid, 256, 0, stream>>>(xb, rel_rp, rel_src, r, nr, h1b);
        else
            gather_kernel<0><<<gather_grid, 256, 0, stream>>>(x, rel_rp, rel_src, r, nr, h1b);

        gather_kernel<1><<<gather_grid, 256, 0, stream>>>(h1b, rel_rp, rel_src, r, nr, h2b);

        if (use_xb)
            gemm_mfma_kernel<1><<<gemm_grid, 256, 0, stream>>>(
                xb, h1b, h2b, Wpk + (size_t)r * 3072 * 8,
                b + (size_t)r * D_OUT, out + (size_t)r * D_OUT);
        else
            gemm_mfma_kernel<0><<<gemm_grid, 256, 0, stream>>>(
                x, h1b, h2b, Wpk + (size_t)r * 3072 * 8,
                b + (size_t)r * D_OUT, out + (size_t)r * D_OUT);
    }
}

// Round 11
// 683.626 us; speedup vs baseline: 1.1148x; 1.1148x over previous
//
#include <hip/hip_runtime.h>
#include <stdint.h>

#define N_NODES 100000
#define N_EDGES 1000000
#define D_IN 128
#define D_OUT 64
#define N_REL 4
#define OUT_STRIDE (N_REL * D_OUT)   // 256

#define M_SCAN (N_REL * N_NODES)     // 400000
#define SCHUNK 2048
#define NSB ((M_SCAN + SCHUNK - 1) / SCHUNK)   // 196 (<=256)
#define REL_CAP 2200000              // >= well above E[2M] masked entries

typedef short s16x8 __attribute__((ext_vector_type(8)));
typedef float f32x4 __attribute__((ext_vector_type(4)));

__device__ inline float b2f(unsigned short u) {
    union { unsigned int i; float f; } v;
    v.i = ((unsigned int)u) << 16;
    return v.f;
}
__device__ inline unsigned short f2b(float f) {
    union { float f; unsigned int i; } v;
    v.f = f;
    unsigned int r = v.i + 0x7FFF + ((v.i >> 16) & 1);   // rne
    return (unsigned short)(r >> 16);
}

// flag=1 if mask is 1-byte bools, 0 if int32
__global__ __launch_bounds__(256) void detect_mask_kernel(const uint8_t* __restrict__ mask,
                                                          int* __restrict__ flag) {
    int any = 0;
    for (int i = threadIdx.x; i < 65536; i += 256)
        if ((i & 3) && mask[i]) any = 1;
    if (any) atomicOr(flag, 1);
}

__device__ inline bool read_mask(const uint8_t* mask8, int bytemode, size_t idx) {
    return bytemode ? (mask8[idx] != 0) : (((const int*)mask8)[idx] != 0);
}

// all 4 masked in-degrees in ONE u64 atomic per edge (16-bit fields)
__global__ __launch_bounds__(256) void deg_kernel(const int* __restrict__ dst,
                                                  const uint8_t* __restrict__ mask,
                                                  const int* __restrict__ flag,
                                                  unsigned long long* __restrict__ degu) {
    int e = blockIdx.x * blockDim.x + threadIdx.x;
    if (e >= N_EDGES) return;
    int bm = *flag;
    int d = dst[e];
    unsigned long long inc = 0;
    if (read_mask(mask, bm, (size_t)0 * N_EDGES + e)) inc += 1ull;
    if (read_mask(mask, bm, (size_t)1 * N_EDGES + e)) inc += 1ull << 16;
    if (read_mask(mask, bm, (size_t)2 * N_EDGES + e)) inc += 1ull << 32;
    if (read_mask(mask, bm, (size_t)3 * N_EDGES + e)) inc += 1ull << 48;
    if (inc) atomicAdd(&degu[d], inc);
}

// norm[r*N+n] = 1/sqrt(max(deg_r[n],1))
__global__ __launch_bounds__(256) void norm_kernel(const unsigned long long* __restrict__ degu,
                                                   float* __restrict__ norm) {
    int n = blockIdx.x * blockDim.x + threadIdx.x;
    if (n >= N_NODES) return;
    unsigned long long u = degu[n];
#pragma unroll
    for (int r = 0; r < N_REL; ++r) {
        float dg = (float)((u >> (16 * r)) & 0xFFFF);
        norm[r * N_NODES + n] = 1.0f / sqrtf(fmaxf(dg, 1.0f));
    }
}

__device__ inline int scan_val(const unsigned long long* degu, int i) {
    int r = i / N_NODES;
    int n = i - r * N_NODES;
    return (int)((degu[n] >> (16 * r)) & 0xFFFF);
}

// ---- 3-phase exclusive scan over concatenated masked degrees [4N] ----
__global__ __launch_bounds__(256) void scan_reduce_kernel(const unsigned long long* __restrict__ degu,
                                                          int* __restrict__ bsum) {
    __shared__ int sm[256];
    int b = blockIdx.x, t = threadIdx.x;
    int base = b * SCHUNK + t * 8;
    int s = 0;
#pragma unroll
    for (int i = 0; i < 8; ++i) {
        int idx = base + i;
        if (idx < M_SCAN) s += scan_val(degu, idx);
    }
    sm[t] = s;
    __syncthreads();
    for (int st = 128; st > 0; st >>= 1) {
        if (t < st) sm[t] += sm[t + st];
        __syncthreads();
    }
    if (t == 0) bsum[b] = sm[0];
}

__global__ __launch_bounds__(256) void scan_mid_kernel(const int* __restrict__ bsum,
                                                       int* __restrict__ boff,
                                                       int* __restrict__ rel_rp) {
    __shared__ int sm[256];
    int t = threadIdx.x;
    int v = (t < NSB) ? bsum[t] : 0;
    sm[t] = v;
    __syncthreads();
    for (int st = 1; st < 256; st <<= 1) {
        int u = (t >= st) ? sm[t - st] : 0;
        __syncthreads();
        sm[t] += u;
        __syncthreads();
    }
    if (t < NSB) boff[t] = sm[t] - v;              // exclusive block offset
    if (t == NSB - 1) rel_rp[M_SCAN] = sm[t];      // total masked entries
}

__global__ __launch_bounds__(256) void scan_final_kernel(const unsigned long long* __restrict__ degu,
                                                         const int* __restrict__ boff,
                                                         int* __restrict__ rel_rp,
                                                         int* __restrict__ cursor) {
    __shared__ int sm[256];
    int b = blockIdx.x, t = threadIdx.x;
    int base = b * SCHUNK + t * 8;
    int v[8];
    int s = 0;
#pragma unroll
    for (int i = 0; i < 8; ++i) {
        int idx = base + i;
        v[i] = (idx < M_SCAN) ? scan_val(degu, idx) : 0;
        s += v[i];
    }
    sm[t] = s;
    __syncthreads();
    for (int st = 1; st < 256; st <<= 1) {
        int u = (t >= st) ? sm[t - st] : 0;
        __syncthreads();
        sm[t] += u;
        __syncthreads();
    }
    int run = sm[t] - s + boff[b];
#pragma unroll
    for (int i = 0; i < 8; ++i) {
        int idx = base + i;
        if (idx < M_SCAN) { rel_rp[idx] = run; cursor[idx] = run; run += v[i]; }
    }
}

// compacted per-relation CSR: only masked edges, store src only
__global__ __launch_bounds__(256) void fill_kernel(const int* __restrict__ src,
                                                   const int* __restrict__ dst,
                                                   const uint8_t* __restrict__ mask,
                                                   const int* __restrict__ flag,
                                                   int* __restrict__ cursor,
                                                   int* __restrict__ rel_src) {
    int e = blockIdx.x * blockDim.x + threadIdx.x;
    if (e >= N_EDGES) return;
    int bm = *flag;
    int s = src[e], d = dst[e];
#pragma unroll
    for (int r = 0; r < N_REL; ++r) {
        if (read_mask(mask, bm, (size_t)r * N_EDGES + e)) {
            int pos = atomicAdd(&cursor[r * N_NODES + d], 1);
            rel_src[pos] = s;
        }
    }
}

// pack W[r][384][64] fp32 -> Wpk frags [r][ks][nb][lane][8] bf16
__global__ __launch_bounds__(256) void pack_w_kernel(const float* __restrict__ W,
                                                     unsigned short* __restrict__ Wpk) {
    int t = blockIdx.x * blockDim.x + threadIdx.x;   // 12288
    if (t >= N_REL * 12 * 4 * 64) return;
    int lane = t & 63;
    int nb   = (t >> 6) & 3;
    int ks   = (t >> 8) % 12;
    int r    = t / 3072;
    const float* Wr = W + (size_t)r * 384 * 64;
    int k0 = ks * 32 + (lane >> 4) * 8;
    int n  = nb * 16 + (lane & 15);
    unsigned short* o = Wpk + (size_t)t * 8;
#pragma unroll
    for (int i = 0; i < 8; ++i)
        o[i] = f2b(Wr[(size_t)(k0 + i) * 64 + n]);
}

// x fp32 -> bf16
__global__ __launch_bounds__(256) void xb_kernel(const float* __restrict__ x,
                                                 unsigned short* __restrict__ xb) {
    int i = blockIdx.x * blockDim.x + threadIdx.x;
    if (i >= N_NODES * (D_IN / 4)) return;
    float4 v = ((const float4*)x)[i];
    ushort4 u;
    u.x = f2b(v.x); u.y = f2b(v.y); u.z = f2b(v.z); u.w = f2b(v.w);
    ((ushort4*)xb)[i] = u;
}

// one hop over compacted CSR: hout[d] = bf16( norm[d] * sum_e norm[src]*hin[src] )
// ONE 16-lane group per node (4 nodes/wave); group walks its node's edges
// serially; 8 features/lane (16B bf16 / 32B fp32 per lane); width-16 shfl
// broadcast (source lane always within own active group). No butterfly.
template <int BF16IN>
__global__ __launch_bounds__(256) void gather_kernel(const void* __restrict__ hin_,
                                                     const int* __restrict__ rp,   // +r*N
                                                     const int* __restrict__ rel_src,
                                                     const float* __restrict__ normr,
                                                     unsigned short* __restrict__ hout) {
    const int lane = threadIdx.x & 63;
    const int wave = (blockIdx.x * blockDim.x + threadIdx.x) >> 6;
    const int g    = lane >> 4;            // node-slot within wave
    const int l16  = lane & 15;
    const int node = wave * 4 + g;
    const int fb   = l16 * 8;              // feature base (8 feats/lane)

    const bool valid = (node < N_NODES);
    int e0 = valid ? rp[node] : 0;
    int e1 = valid ? rp[node + 1] : 0;

    float a[8];
#pragma unroll
    for (int j = 0; j < 8; ++j) a[j] = 0.0f;

    for (int base = e0; base < e1; base += 16) {
        int m = min(16, e1 - base);                  // group-uniform
        int   s_l = (l16 < m) ? rel_src[base + l16] : 0;
        float w_l = (l16 < m) ? normr[s_l] : 0.0f;

        for (int i = 0; i < m; ++i) {                // group-uniform trip count
            int   s = __shfl(s_l, i, 16);            // full-exec within group
            float w = __shfl(w_l, i, 16);
            if (BF16IN) {
                s16x8 v = *(const s16x8*)((const unsigned short*)hin_ +
                                          (size_t)s * D_IN + fb);
#pragma unroll
                for (int j = 0; j < 8; ++j)
                    a[j] += w * b2f((unsigned short)v[j]);
            } else {
                const float* xp = (const float*)hin_ + (size_t)s * D_IN + fb;
                float4 v0 = *(const float4*)xp;
                float4 v1 = *(const float4*)(xp + 4);
                a[0] += w * v0.x; a[1] += w * v0.y;
                a[2] += w * v0.z; a[3] += w * v0.w;
                a[4] += w * v1.x; a[5] += w * v1.y;
                a[6] += w * v1.z; a[7] += w * v1.w;
            }
        }
    }

    if (valid) {
        float c = normr[node];
        s16x8 r;
#pragma unroll
        for (int j = 0; j < 8; ++j) r[j] = (short)f2b(a[j] * c);
        *(s16x8*)(hout + (size_t)node * D_IN + fb) = r;
    }
}

// MFMA GEMM: out[n][j] = relu(bias[j] + sum_k [x|h1|h2][n][k] W[k][j])
template <int XB16>
__global__ __launch_bounds__(256) void gemm_mfma_kernel(const void* __restrict__ x_,
                                                        const unsigned short* __restrict__ h1b,
                                                        const unsigned short* __restrict__ h2b,
                                                        const unsigned short* __restrict__ Wpk,
                                                        const float* __restrict__ bias,
                                                        float* __restrict__ out) {
    const int wave = threadIdx.x >> 6;
    const int lane = threadIdx.x & 63;
    const int rb   = blockIdx.x * 64 + wave * 16;
    const int row  = min(rb + (lane & 15), N_NODES - 1);
    const int kq   = (lane >> 4) * 8;

    f32x4 acc0 = {0.f, 0.f, 0.f, 0.f};
    f32x4 acc1 = {0.f, 0.f, 0.f, 0.f};
    f32x4 acc2 = {0.f, 0.f, 0.f, 0.f};
    f32x4 acc3 = {0.f, 0.f, 0.f, 0.f};

    const s16x8* Wf = (const s16x8*)Wpk;

#pragma unroll
    for (int ks = 0; ks < 12; ++ks) {
        s16x8 a;
        const int koff = (ks & 3) * 32 + kq;
        if (ks < 4) {
            if (XB16) {
                a = *(const s16x8*)((const unsigned short*)x_ + (size_t)row * D_IN + koff);
            } else {
                const float* p = (const float*)x_ + (size_t)row * D_IN + koff;
                float4 f0 = *(const float4*)p;
                float4 f1 = *(const float4*)(p + 4);
                a[0] = (short)f2b(f0.x); a[1] = (short)f2b(f0.y);
                a[2] = (short)f2b(f0.z); a[3] = (short)f2b(f0.w);
                a[4] = (short)f2b(f1.x); a[5] = (short)f2b(f1.y);
                a[6] = (short)f2b(f1.z); a[7] = (short)f2b(f1.w);
            }
        } else {
            const unsigned short* hp = (ks < 8) ? h1b : h2b;
            a = *(const s16x8*)(hp + (size_t)row * D_IN + koff);
        }
        const s16x8* bks = Wf + ks * 256 + lane;
        acc0 = __builtin_amdgcn_mfma_f32_16x16x32_bf16(a, bks[0],   acc0, 0, 0, 0);
        acc1 = __builtin_amdgcn_mfma_f32_16x16x32_bf16(a, bks[64],  acc1, 0, 0, 0);
        acc2 = __builtin_amdgcn_mfma_f32_16x16x32_bf16(a, bks[128], acc2, 0, 0, 0);
        acc3 = __builtin_amdgcn_mfma_f32_16x16x32_bf16(a, bks[192], acc3, 0, 0, 0);
    }

    const int orow0 = rb + (lane >> 4) * 4;
    const int jc    = lane & 15;
    f32x4 accs[4] = {acc0, acc1, acc2, acc3};
#pragma unroll
    for (int nb = 0; nb < 4; ++nb) {
        float bz = bias[nb * 16 + jc];
#pragma unroll
        for (int i = 0; i < 4; ++i) {
            int n = orow0 + i;
            if (n < N_NODES)
                out[(size_t)n * OUT_STRIDE + nb * 16 + jc] = fmaxf(accs[nb][i] + bz, 0.0f);
        }
    }
}

extern "C" void kernel_launch(void* const* d_in, const int* in_sizes, int n_in,
                              void* d_out, int out_size, void* d_ws, size_t ws_size,
                              hipStream_t stream) {
    const float*   x    = (const float*)d_in[0];
    const int*     src  = (const int*)d_in[1];
    const int*     dst  = (const int*)d_in[2];
    const uint8_t* mask = (const uint8_t*)d_in[3];
    const float*   W    = (const float*)d_in[4];     // [4][384][64]
    const float*   b    = (const float*)d_in[5];     // [4][64]
    float*         out  = (float*)d_out;             // [N][256]

    // ws: flag[64]i | degu[N]u64 | norm[4N]f | rel_rp[4N+16]i | bsum[256] |
    //     boff[256] | rel_src[REL_CAP]i | Wpk bf16 | h1b bf16 | h2b bf16 |
    //     xb bf16 (optional).  cursor aliases h1b (dead before gathers).
    int*                flag    = (int*)d_ws;
    unsigned long long* degu    = (unsigned long long*)((char*)d_ws + 256);
    float*              norm    = (float*)(degu + N_NODES);
    int*                rel_rp  = (int*)(norm + (size_t)N_REL * N_NODES);
    int*                bsum    = rel_rp + M_SCAN + 16;
    int*                boff    = bsum + 256;
    int*                rel_src = boff + 256;
    unsigned short*     Wpk     = (unsigned short*)(rel_src + REL_CAP);
    unsigned short*     h1b     = Wpk + 12288 * 8;
    unsigned short*     h2b     = h1b + (size_t)N_NODES * D_IN;
    unsigned short*     xb      = h2b + (size_t)N_NODES * D_IN;
    int*                cursor  = (int*)h1b;   // alias: used only pre-gather

    const size_t need_xb = (size_t)((char*)(xb + (size_t)N_NODES * D_IN) - (char*)d_ws);
    const int use_xb = (ws_size >= need_xb);

    // zero flag + degu
    hipMemsetAsync(d_ws, 0, 256 + (size_t)N_NODES * sizeof(unsigned long long), stream);

    detect_mask_kernel<<<1, 256, 0, stream>>>(mask, flag);
    deg_kernel<<<(N_EDGES + 255) / 256, 256, 0, stream>>>(dst, mask, flag, degu);
    norm_kernel<<<(N_NODES + 255) / 256, 256, 0, stream>>>(degu, norm);

    scan_reduce_kernel<<<NSB, 256, 0, stream>>>(degu, bsum);
    scan_mid_kernel<<<1, 256, 0, stream>>>(bsum, boff, rel_rp);
    scan_final_kernel<<<NSB, 256, 0, stream>>>(degu, boff, rel_rp, cursor);

    fill_kernel<<<(N_EDGES + 255) / 256, 256, 0, stream>>>(src, dst, mask, flag,
                                                           cursor, rel_src);
    pack_w_kernel<<<48, 256, 0, stream>>>(W, Wpk);
    if (use_xb)
        xb_kernel<<<(N_NODES * (D_IN / 4) + 255) / 256, 256, 0, stream>>>(x, xb);

    const int gather_grid = (N_NODES + 15) / 16;   // 16 nodes per 256-thread block
    const int gemm_grid   = (N_NODES + 63) / 64;

    for (int r = 0; r < N_REL; ++r) {
        const float* nr  = norm + (size_t)r * N_NODES;
        const int*   rpr = rel_rp + (size_t)r * N_NODES;

        if (use_xb)
            gather_kernel<1><<<gather_grid, 256, 0, stream>>>(xb, rpr, rel_src, nr, h1b);
        else
            gather_kernel<0><<<gather_grid, 256, 0, stream>>>(x, rpr, rel_src, nr, h1b);

        gather_kernel<1><<<gather_grid, 256, 0, stream>>>(h1b, rpr, rel_src, nr, h2b);

        if (use_xb)
            gemm_mfma_kernel<1><<<gemm_grid, 256, 0, stream>>>(
                xb, h1b, h2b, Wpk + (size_t)r * 3072 * 8,
                b + (size_t)r * D_OUT, out + (size_t)r * D_OUT);
        else
            gemm_mfma_kernel<0><<<gemm_grid, 256, 0, stream>>>(
                x, h1b, h2b, Wpk + (size_t)r * 3072 * 8,
                b + (size_t)r * D_OUT, out + (size_t)r * D_OUT);
    }
}